// Round 9
// baseline (187.870 us; speedup 1.0000x reference)
//
#include <hip/hip_runtime.h>
#include <hip/hip_bf16.h>

typedef __bf16 bf16x8 __attribute__((ext_vector_type(8)));
typedef float f32x4 __attribute__((ext_vector_type(4)));
typedef float f32x16 __attribute__((ext_vector_type(16)));
typedef unsigned short ushort_t;
typedef unsigned int uint2v __attribute__((ext_vector_type(2)));

#define DEVI __device__ __forceinline__

static constexpr int KDIM = 1024;   // d_model
static constexpr int SEQ  = 2048;

DEVI ushort_t f2bf(float f) {
  union { float f; unsigned u; } a; a.f = f;
  unsigned u = a.u;
  return (ushort_t)((u + 0x7FFFu + ((u >> 16) & 1u)) >> 16);
}

DEVI unsigned cvtpk(float lo, float hi) {   // word = {bf16(hi)<<16 | bf16(lo)}
  unsigned r;
  asm("v_cvt_pk_bf16_f32 %0, %1, %2" : "=v"(r) : "v"(lo), "v"(hi));
  return r;
}

// validated permlane path (m240/m214): builtin, compiler handles hazards.
DEVI uint2v plswap(unsigned a, unsigned b) {
  return __builtin_amdgcn_permlane32_swap(a, b, 0, 0);
}
DEVI float swap_max(float x) {
  union { float f; unsigned u; } a; a.f = x;
  const uint2v r = plswap(a.u, a.u);
  union { unsigned u; float f; } p0, p1; p0.u = r[0]; p1.u = r[1];
  return fmaxf(p0.f, p1.f);
}
DEVI float swap_sum(float x) {
  union { float f; unsigned u; } a; a.f = x;
  const uint2v r = plswap(a.u, a.u);
  union { unsigned u; float f; } p0, p1; p0.u = r[0]; p1.u = r[1];
  return p0.f + p1.f;
}

DEVI void gload16(const ushort_t* g, ushort_t* l) {
  __builtin_amdgcn_global_load_lds(
      (const __attribute__((address_space(1))) void*)g,
      (__attribute__((address_space(3))) void*)l,
      16, 0, 0);
}

// ---------------- fused casts: x (1M float4) then Wq|Wk|Wv|Wo (1M float4) ----------------
__global__ void cast_all(const float* __restrict__ x,
                         const float* __restrict__ w0, const float* __restrict__ w1,
                         const float* __restrict__ w2, const float* __restrict__ w3,
                         ushort_t* __restrict__ xb, ushort_t* __restrict__ wb) {
  const int i = blockIdx.x * 256 + threadIdx.x;   // [0, 2M)
  float4 v; ushort_t* dst; int idx;
  if (i < (1 << 20)) {
    v = ((const float4*)x)[i]; dst = xb; idx = i;
  } else {
    const int j = i - (1 << 20);
    const int which = j >> 18;
    const float* w = which == 0 ? w0 : which == 1 ? w1 : which == 2 ? w2 : w3;
    v = ((const float4*)w)[j & 262143]; dst = wb; idx = j;
  }
  ushort4 o;
  o.x = f2bf(v.x); o.y = f2bf(v.y); o.z = f2bf(v.z); o.w = f2bf(v.w);
  ((ushort4*)dst)[idx] = o;
}

// ---------------- QKV GEMM: 256x256 tile, 8-phase counted-vmcnt schedule ----------------
DEVI void stage_half(const ushort_t* __restrict__ G, int rowbase, int kcol,
                     ushort_t* lbase, int tid) {
#pragma unroll
  for (int rd = 0; rd < 2; ++rd) {
    const int row = rd * 128 + (tid >> 2), cg = tid & 3;
    const int gcol = kcol + ((cg ^ ((row >> 1) & 3)) << 3);
    gload16(G + (size_t)(rowbase + row) * 1024 + gcol, lbase + row * 32 + cg * 8);
  }
}

__global__ __launch_bounds__(512, 2) void gemm256_qkv(const ushort_t* __restrict__ xb,
                                                      const ushort_t* __restrict__ wb,
                                                      ushort_t* __restrict__ qfo,
                                                      ushort_t* __restrict__ kfo,
                                                      ushort_t* __restrict__ vfo) {
  __shared__ ushort_t sm[2][2][2][8192];
  const int tid = threadIdx.x;
  const int wid = tid >> 6, l = tid & 63;
  const int wm = wid >> 2, wn = wid & 3;
  const int lg = l >> 4, ll = l & 15;
  // bijective XCD swizzle: nwg = 192 = 8 * 24
  const int orig = blockIdx.x;
  const int wg = (orig & 7) * 24 + (orig >> 3);

  int m0, n0;
  const ushort_t *Ap, *Bp;
  bool isV;
  if (wg < 128) {          // Q^T / K^T blocks
    m0 = (wg >> 4) * 256;  // W-row: 0..1023 = Wq, 1024..2047 = Wk
    n0 = (wg & 15) * 256;  // s: 0..4095
    Ap = wb; Bp = xb; isV = false;
  } else {                 // V blocks (normal orientation)
    const int lo = wg - 128;
    m0 = (lo >> 2) * 256;  // s rows 0..4095
    n0 = (lo & 3) * 256;   // V out-col 0..1023
    Ap = xb; Bp = wb + (size_t)2048 * 1024; isV = true;
  }

  f32x4 acc[8][4];
#pragma unroll
  for (int i = 0; i < 8; ++i)
#pragma unroll
    for (int j = 0; j < 4; ++j) acc[i][j] = f32x4{0.f, 0.f, 0.f, 0.f};

#define STG(T, MAT, KH) do { if ((T) < 16) \
    stage_half((MAT) ? Bp : Ap, (MAT) ? n0 : m0, (T) * 64 + (KH) * 32, \
               &sm[(T) & 1][MAT][KH][0], tid); } while (0)
#define BARX do { asm volatile("" ::: "memory"); __builtin_amdgcn_s_barrier(); \
                  asm volatile("" ::: "memory"); } while (0)
#define PHASE(P, KH, MH, STG_STMT, WAIT_STMT) do {                              \
    bf16x8 af_[4], bf_[4];                                                      \
    _Pragma("unroll")                                                           \
    for (int mr = 0; mr < 4; ++mr) {                                            \
      const int ra = wm * 128 + ((MH) * 4 + mr) * 16 + ll;                      \
      af_[mr] = *(const bf16x8*)&sm[P][0][KH][ra * 32 + ((lg ^ ((ra >> 1) & 3)) << 3)]; \
    }                                                                           \
    _Pragma("unroll")                                                           \
    for (int nr = 0; nr < 4; ++nr) {                                            \
      const int rb = wn * 64 + nr * 16 + ll;                                    \
      bf_[nr] = *(const bf16x8*)&sm[P][1][KH][rb * 32 + ((lg ^ ((rb >> 1) & 3)) << 3)]; \
    }                                                                           \
    STG_STMT;                                                                   \
    BARX;                                                                       \
    __builtin_amdgcn_s_setprio(1);                                              \
    _Pragma("unroll")                                                           \
    for (int mr = 0; mr < 4; ++mr)                                              \
      _Pragma("unroll")                                                         \
      for (int nr = 0; nr < 4; ++nr)                                            \
        acc[(MH) * 4 + mr][nr] = __builtin_amdgcn_mfma_f32_16x16x32_bf16(       \
            af_[mr], bf_[nr], acc[(MH) * 4 + mr][nr], 0, 0, 0);                 \
    __builtin_amdgcn_s_setprio(0);                                              \
    WAIT_STMT;                                                                  \
    BARX;                                                                       \
  } while (0)
#define WAIT4 asm volatile("s_waitcnt vmcnt(4)" ::: "memory")
#define WAIT0 asm volatile("s_waitcnt vmcnt(0)" ::: "memory")

  // prologue: tile0 all 4 halves + tile1 k0 halves; land tile0, leave tile1-k0 in flight
  STG(0, 0, 0); STG(0, 1, 0); STG(0, 0, 1); STG(0, 1, 1); STG(1, 0, 0); STG(1, 1, 0);
  WAIT4;
  BARX;

  for (int I = 0; I < 7; ++I) {
    const int T = 2 * I;
    PHASE(0, 0, 0, STG(T + 1, 0, 1), );
    PHASE(0, 0, 1, STG(T + 1, 1, 1), );
    PHASE(0, 1, 0, STG(T + 2, 0, 0), );
    PHASE(0, 1, 1, STG(T + 2, 1, 0), WAIT4);
    PHASE(1, 0, 0, STG(T + 2, 0, 1), );
    PHASE(1, 0, 1, STG(T + 2, 1, 1), );
    PHASE(1, 1, 0, STG(T + 3, 0, 0), );
    PHASE(1, 1, 1, STG(T + 3, 1, 0), WAIT4);
  }
  PHASE(0, 0, 0, STG(15, 0, 1), );
  PHASE(0, 0, 1, STG(15, 1, 1), );
  PHASE(0, 1, 0, , );
  PHASE(0, 1, 1, , WAIT0);
  PHASE(1, 0, 0, , );
  PHASE(1, 0, 1, , );
  PHASE(1, 1, 0, , );
  PHASE(1, 1, 1, , );

#undef STG
#undef PHASE
#undef WAIT4
#undef WAIT0
#undef BARX

  // ---------------- epilogue ----------------
  if (!isV) {
    const int whichK = m0 >> 10;             // 0 = Q, 1 = K
    const int lgh = lg >> 1, lgb = lg & 1;
    ushort_t* const dstb = whichK ? kfo : qfo;
#pragma unroll
    for (int mr = 0; mr < 8; ++mr) {
      const int dout = (m0 & 1023) + wm * 128 + mr * 16;   // +4lg+r implicit
      const int h = dout >> 6;
      const int ks = (dout >> 4) & 3;
#pragma unroll
      for (int nr = 0; nr < 4; ++nr) {
        const int s = n0 + wn * 64 + nr * 16 + ll;
        const int b = s >> 11, s2 = s & 2047;
        const size_t bh = (size_t)(b * 16 + h);
        size_t addr;
        if (whichK == 0)
          addr = ((bh * 64 + (s2 >> 5)) * 4 + ks) * 512 + (lgh * 32 + (s2 & 31)) * 8 + lgb * 4;
        else
          addr = ((bh * 32 + (s2 >> 6)) * 8 + ((s2 >> 5) & 1) * 4 + ks) * 512 +
                 (lgh * 32 + (s2 & 31)) * 8 + lgb * 4;
        const unsigned u0 = cvtpk(acc[mr][nr][0], acc[mr][nr][1]);
        const unsigned u1 = cvtpk(acc[mr][nr][2], acc[mr][nr][3]);
        *(uint2v*)(dstb + addr) = uint2v{u0, u1};
      }
    }
  } else {
#pragma unroll
    for (int mr = 0; mr < 8; ++mr) {
#pragma unroll
      for (int nr = 0; nr < 4; ++nr) {
        const int gm0 = m0 + wm * 128 + mr * 16 + 4 * lg;  // s
        const int gn = n0 + wn * 64 + nr * 16 + ll;        // out-col 0..1023
        const int h = gn >> 6, d = gn & 63;
        const int b = gm0 >> 11, s0 = gm0 & 2047;
        const size_t bh = (size_t)(b * 16 + h);
        const size_t base = ((bh * 32 + (s0 >> 6)) * 8 + (d >> 5) * 4 + ((s0 >> 4) & 3)) * 512 +
                            (((s0 >> 3) & 1) * 32 + (d & 31)) * 8 + (s0 & 7);
        const unsigned u0 = cvtpk(acc[mr][nr][0], acc[mr][nr][1]);
        const unsigned u1 = cvtpk(acc[mr][nr][2], acc[mr][nr][3]);
        *(uint2v*)(vfo + base) = uint2v{u0, u1};
      }
    }
  }
}

// ---------------- output projection GEMM: 128x128 tile (m97 structure) ----------------
__global__ __launch_bounds__(256, 3) void gemm_out(const ushort_t* __restrict__ A,
                                                   const ushort_t* __restrict__ Bm,
                                                   float* __restrict__ ofp) {
  __shared__ ushort_t smA[128 * 64];
  __shared__ ushort_t smB[128 * 64];
  const int tid = threadIdx.x;
  const int w = tid >> 6, l = tid & 63;
  const int lg = l >> 4, ll = l & 15;
  const int lr = l >> 3, lc = (l & 7) * 8;
  const int m0 = blockIdx.y * 128, n0 = blockIdx.x * 128;
  const int wm = (w >> 1) * 64, wn = (w & 1) * 64;

  f32x4 acc[4][4];
#pragma unroll
  for (int i = 0; i < 4; ++i)
#pragma unroll
    for (int j = 0; j < 4; ++j) acc[i][j] = f32x4{0.f, 0.f, 0.f, 0.f};

  for (int k0 = 0; k0 < KDIM; k0 += 64) {
    __syncthreads();
#pragma unroll
    for (int i = 0; i < 4; ++i) {
      const int ci = w * 4 + i;
      gload16(A  + (size_t)(m0 + ci * 8 + lr) * KDIM + k0 + lc, smA + ci * 512);
      gload16(Bm + (size_t)(n0 + ci * 8 + lr) * KDIM + k0 + lc, smB + ci * 512);
    }
    __syncthreads();
#pragma unroll
    for (int ks = 0; ks < 2; ++ks) {
      bf16x8 af[4], bfr[4];
#pragma unroll
      for (int t = 0; t < 4; ++t) {
        af[t]  = *(const bf16x8*)(smA + (wm + t * 16 + ll) * 64 + ks * 32 + lg * 8);
        bfr[t] = *(const bf16x8*)(smB + (wn + t * 16 + ll) * 64 + ks * 32 + lg * 8);
      }
      __builtin_amdgcn_s_setprio(1);
#pragma unroll
      for (int i = 0; i < 4; ++i)
#pragma unroll
        for (int j = 0; j < 4; ++j)
          acc[i][j] = __builtin_amdgcn_mfma_f32_16x16x32_bf16(af[i], bfr[j], acc[i][j], 0, 0, 0);
      __builtin_amdgcn_s_setprio(0);
    }
  }

#pragma unroll
  for (int i = 0; i < 4; ++i)
#pragma unroll
    for (int j = 0; j < 4; ++j) {
      const int gm0 = m0 + wm + i * 16 + 4 * lg;
      const int gn = n0 + wn + j * 16 + ll;
#pragma unroll
      for (int r = 0; r < 4; ++r)
        ofp[(size_t)(gm0 + r) * 1024 + gn] = acc[i][j][r];
    }
}

// ---------------- causal flash attention v5: dual-chain per wave, shared K/V ----------------
// grid (16, 32): x = 128-row q-tile, y = bh. Block = 128 thr (2 waves). Each wave owns
// TWO 32-row chains (rows w*32 and 64+w*32): independent dep-chains interleave on the
// MFMA/VALU pipes, K/V fragment loads amortize over both. Free-running, no LDS.
DEVI void sm_pack(f32x16* sc, float& mi, float& li, f32x16* oT, bf16x8* pf) {
  const float SCL2 = 0.18033688011112042f;   // (1/8) * log2(e)
  float t8[8];
#pragma unroll
  for (int r = 0; r < 8; ++r)
    t8[r] = fmaxf(fmaxf(sc[0][r], sc[0][r + 8]), fmaxf(sc[1][r], sc[1][r + 8]));
  float mx = fmaxf(fmaxf(fmaxf(t8[0], t8[1]), fmaxf(t8[2], t8[3])),
                   fmaxf(fmaxf(t8[4], t8[5]), fmaxf(t8[6], t8[7])));
  mx = swap_max(mx);

  if (!__all(mx <= mi + 44.0f)) {    // defer-max (T13), THR=8 exp2-domain
    const float mnew = fmaxf(mi, mx);
    const float al = __builtin_amdgcn_exp2f((mi - mnew) * SCL2);
    li *= al;
#pragma unroll
    for (int dh = 0; dh < 2; ++dh)
#pragma unroll
      for (int r = 0; r < 16; ++r) oT[dh][r] *= al;
    mi = mnew;
  }

  const float ms = mi * SCL2;
#pragma unroll
  for (int h2 = 0; h2 < 2; ++h2)
#pragma unroll
    for (int r = 0; r < 16; ++r)
      sc[h2][r] = __builtin_amdgcn_exp2f(__builtin_fmaf(sc[h2][r], SCL2, -ms));
  float s8[8];
#pragma unroll
  for (int r = 0; r < 8; ++r)
    s8[r] = (sc[0][r] + sc[0][r + 8]) + (sc[1][r] + sc[1][r + 8]);
  float sum = ((s8[0] + s8[1]) + (s8[2] + s8[3])) + ((s8[4] + s8[5]) + (s8[6] + s8[7]));
  li += swap_sum(sum);

#pragma unroll
  for (int m = 0; m < 4; ++m) {      // T12 pack
    const int H = m >> 1, base = (m & 1) * 8;
    const unsigned a0 = cvtpk(sc[H][base + 0], sc[H][base + 1]);
    const unsigned a1 = cvtpk(sc[H][base + 2], sc[H][base + 3]);
    const unsigned a2 = cvtpk(sc[H][base + 4], sc[H][base + 5]);
    const unsigned a3 = cvtpk(sc[H][base + 6], sc[H][base + 7]);
    const uint2v r02 = plswap(a0, a2);
    const uint2v r13 = plswap(a1, a3);
    union { unsigned u[4]; bf16x8 v; } cv;
    cv.u[0] = r02[0]; cv.u[1] = r13[0]; cv.u[2] = r02[1]; cv.u[3] = r13[1];
    pf[m] = cv.v;
  }
}

DEVI void mask_tile(f32x16* sc, int thr0) {
#pragma unroll
  for (int r = 0; r < 16; ++r) {
    const int cr = (r & 3) + 8 * (r >> 2);
    if (cr > thr0)      sc[0][r] = -3.0e38f;
    if (cr > thr0 - 32) sc[1][r] = -3.0e38f;
  }
}

__global__ __launch_bounds__(128, 2) void attn_fwd(const ushort_t* __restrict__ Qf,
                                                   const ushort_t* __restrict__ Kf,
                                                   const ushort_t* __restrict__ Vf,
                                                   ushort_t* __restrict__ ao) {
  const int tid = threadIdx.x;
  const int w = tid >> 6, l = tid & 63;
  const int l31 = l & 31, hi = l >> 5;
  const int bh = blockIdx.y;
  const int qx = ((bh >> 4) & 1) ? (15 - (int)blockIdx.x) : (int)blockIdx.x;
  const int q0 = qx * 128;
  const int qA = q0 + w * 32 + l31;          // chain A lane row
  const int qB = qA + 64;                    // chain B lane row

  const ushort_t* Kb = Kf + (size_t)bh * 32 * 8 * 512 + l * 8;
  const ushort_t* Vb = Vf + (size_t)bh * 32 * 8 * 512 + l * 8;
  const ushort_t* QwA = Qf + ((size_t)bh * 64 + (q0 >> 5) + w) * 4 * 512 + l * 8;
  const ushort_t* QwB = QwA + 2 * 4 * 512;

  bf16x8 qfA[4], qfB[4];
#pragma unroll
  for (int ks = 0; ks < 4; ++ks) {
    qfA[ks] = *(const bf16x8*)(QwA + ks * 512);
    qfB[ks] = *(const bf16x8*)(QwB + ks * 512);
  }

  f32x16 oTA[2], oTB[2];
#pragma unroll
  for (int dh = 0; dh < 2; ++dh)
#pragma unroll
    for (int r = 0; r < 16; ++r) { oTA[dh][r] = 0.f; oTB[dh][r] = 0.f; }
  float miA = -3.0e38f, liA = 0.f, miB = -3.0e38f, liB = 0.f;

  const int nA = 2 * qx + 1;   // chain-A trips (both waves); chain B = nA + 1

  bf16x8 kf[8];
#pragma unroll
  for (int f = 0; f < 8; ++f) kf[f] = *(const bf16x8*)(Kb + f * 512);

  for (int kt = 0; kt < nA; ++kt) {
    // shared V loads (issue early, independent)
    const ushort_t* Vt_ = Vb + (size_t)kt * 8 * 512;
    bf16x8 vf[8];
#pragma unroll
    for (int f = 0; f < 8; ++f) vf[f] = *(const bf16x8*)(Vt_ + f * 512);

    // QK^T both chains (shared kf)
    f32x16 scA[2], scB[2];
#pragma unroll
    for (int h2 = 0; h2 < 2; ++h2)
#pragma unroll
      for (int r = 0; r < 16; ++r) { scA[h2][r] = 0.f; scB[h2][r] = 0.f; }
    __builtin_amdgcn_s_setprio(1);
#pragma unroll
    for (int h2 = 0; h2 < 2; ++h2)
#pragma unroll
      for (int ks = 0; ks < 4; ++ks) {
        scA[h2] = __builtin_amdgcn_mfma_f32_32x32x16_bf16(kf[h2 * 4 + ks], qfA[ks], scA[h2], 0, 0, 0);
        scB[h2] = __builtin_amdgcn_mfma_f32_32x32x16_bf16(kf[h2 * 4 + ks], qfB[ks], scB[h2], 0, 0, 0);
      }
    __builtin_amdgcn_s_setprio(0);

    // prefetch next K tile (kt+1 <= nA < 32 always valid for chain B)
    const ushort_t* Kt_ = Kb + (size_t)(kt + 1) * 8 * 512;
    bf16x8 kfn[8];
#pragma unroll
    for (int f = 0; f < 8; ++f) kfn[f] = *(const bf16x8*)(Kt_ + f * 512);

    if (kt == nA - 1) mask_tile(scA, qA - kt * 64 - 4 * hi);   // A's last tile

    bf16x8 pfA[4], pfB[4];
    sm_pack(scA, miA, liA, oTA, pfA);
    sm_pack(scB, miB, liB, oTB, pfB);

    __builtin_amdgcn_s_setprio(1);
#pragma unroll
    for (int dh = 0; dh < 2; ++dh)
#pragma unroll
      for (int m = 0; m < 4; ++m) {
        oTA[dh] = __builtin_amdgcn_mfma_f32_32x32x16_bf16(vf[dh * 4 + m], pfA[m], oTA[dh], 0, 0, 0);
        oTB[dh] = __builtin_amdgcn_mfma_f32_32x32x16_bf16(vf[dh * 4 + m], pfB[m], oTB[dh], 0, 0, 0);
      }
    __builtin_amdgcn_s_setprio(0);

#pragma unroll
    for (int f = 0; f < 8; ++f) kf[f] = kfn[f];
  }

  // tail: chain B's last tile (kt = nA), masked
  {
    const int kt = nA;
    const ushort_t* Vt_ = Vb + (size_t)kt * 8 * 512;
    bf16x8 vf[8];
#pragma unroll
    for (int f = 0; f < 8; ++f) vf[f] = *(const bf16x8*)(Vt_ + f * 512);

    f32x16 scB[2];
#pragma unroll
    for (int h2 = 0; h2 < 2; ++h2)
#pragma unroll
      for (int r = 0; r < 16; ++r) scB[h2][r] = 0.f;
    __builtin_amdgcn_s_setprio(1);
#pragma unroll
    for (int h2 = 0; h2 < 2; ++h2)
#pragma unroll
      for (int ks = 0; ks < 4; ++ks)
        scB[h2] = __builtin_amdgcn_mfma_f32_32x32x16_bf16(kf[h2 * 4 + ks], qfB[ks], scB[h2], 0, 0, 0);
    __builtin_amdgcn_s_setprio(0);

    mask_tile(scB, qB - kt * 64 - 4 * hi);

    bf16x8 pfB[4];
    sm_pack(scB, miB, liB, oTB, pfB);

    __builtin_amdgcn_s_setprio(1);
#pragma unroll
    for (int dh = 0; dh < 2; ++dh)
#pragma unroll
      for (int m = 0; m < 4; ++m)
        oTB[dh] = __builtin_amdgcn_mfma_f32_32x32x16_bf16(vf[dh * 4 + m], pfB[m], oTB[dh], 0, 0, 0);
    __builtin_amdgcn_s_setprio(0);
  }

  // epilogue: normalize + packed 8B stores, both chains
  const int b = bh >> 4, h = bh & 15;
  const float invA = 1.f / liA, invB = 1.f / liB;
  ushort_t* orowA = ao + ((size_t)b * 2048 + qA) * 1024 + h * 64;
  ushort_t* orowB = ao + ((size_t)b * 2048 + qB) * 1024 + h * 64;
#pragma unroll
  for (int dh = 0; dh < 2; ++dh)
#pragma unroll
    for (int rg = 0; rg < 4; ++rg) {
      const unsigned a0 = cvtpk(oTA[dh][4 * rg + 0] * invA, oTA[dh][4 * rg + 1] * invA);
      const unsigned a1 = cvtpk(oTA[dh][4 * rg + 2] * invA, oTA[dh][4 * rg + 3] * invA);
      *(uint2v*)(orowA + dh * 32 + hi * 4 + rg * 8) = uint2v{a0, a1};
      const unsigned b0 = cvtpk(oTB[dh][4 * rg + 0] * invB, oTB[dh][4 * rg + 1] * invB);
      const unsigned b1 = cvtpk(oTB[dh][4 * rg + 2] * invB, oTB[dh][4 * rg + 3] * invB);
      *(uint2v*)(orowB + dh * 32 + hi * 4 + rg * 8) = uint2v{b0, b1};
    }
}

// ---------------- launch ----------------
extern "C" void kernel_launch(void* const* d_in, const int* in_sizes, int n_in,
                              void* d_out, int out_size, void* d_ws, size_t ws_size,
                              hipStream_t stream) {
  (void)in_sizes; (void)n_in; (void)out_size; (void)ws_size;
  const float* x  = (const float*)d_in[0];
  const float* wq = (const float*)d_in[1];
  const float* wk = (const float*)d_in[2];
  const float* wv = (const float*)d_in[3];
  const float* wo = (const float*)d_in[4];

  char* ws = (char*)d_ws;
  ushort_t* xb  = (ushort_t*)ws;                     // 8 MiB; reused as attn-out later
  ushort_t* wb  = (ushort_t*)(ws + (8u  << 20));     // 8 MiB: Wq,Wk,Wv,Wo bf16 contiguous
  ushort_t* qf  = (ushort_t*)(ws + (16u << 20));     // 8 MiB: Q fragment-major
  ushort_t* kf  = (ushort_t*)(ws + (24u << 20));     // 8 MiB: K fragment-major (+1 guard tile read OK)
  ushort_t* vf  = (ushort_t*)(ws + (40u << 20));     // 8 MiB: V fragment-major
  ushort_t* ao  = xb;                                // attention output (b,s,h*64+d)
  float* out = (float*)d_out;

  cast_all   <<<8192, 256, 0, stream>>>(x, wq, wk, wv, wo, xb, wb);
  gemm256_qkv<<<192, 512, 0, stream>>>(xb, wb, qf, kf, vf);
  attn_fwd   <<<dim3(16, 32), 128, 0, stream>>>(qf, kf, vf, ao);
  gemm_out   <<<dim3(8, 32), 256, 0, stream>>>(ao, wb + 3 * 1048576, out);
}